// Round 1
// baseline (175.076 us; speedup 1.0000x reference)
//
#include <hip/hip_runtime.h>

#define BLOCK 256
#define CHUNK 1024   // padding points staged per block; 16 KB LDS (float4 each)

__global__ void dens_zero_kernel(int* __restrict__ out, int n) {
    int i = blockIdx.x * blockDim.x + threadIdx.x;
    if (i < n) out[i] = 0;
}

__global__ __launch_bounds__(BLOCK) void dens_count_kernel(
    const float* __restrict__ pc,   // [N,3] pointcloud
    const float* __restrict__ pad,  // [M,3] pointcloud_padding
    int* __restrict__ out,          // [N] int32 counts
    int N, int M)
{
    __shared__ float4 s_pts[CHUNK];

    const int i      = blockIdx.x * BLOCK + threadIdx.x;
    const int jstart = blockIdx.y * CHUNK;
    const int L      = min(CHUNK, M - jstart);

    // Stage this chunk of padding points into LDS (x,y,z,unused).
    for (int t = threadIdx.x; t < L; t += BLOCK) {
        const int j = jstart + t;
        s_pts[t] = make_float4(pad[3 * j], pad[3 * j + 1], pad[3 * j + 2], 0.0f);
    }
    __syncthreads();

    float px = 0.f, py = 0.f, pz = 0.f;
    if (i < N) {
        px = pc[3 * i];
        py = pc[3 * i + 1];
        pz = pc[3 * i + 2];
    }

    const float r2 = 0.25f;  // (0.5)^2
    int cnt = 0;
    #pragma unroll 4
    for (int t = 0; t < L; ++t) {
        const float4 q = s_pts[t];   // broadcast ds_read_b128, conflict-free
        const float dx = px - q.x;
        const float dy = py - q.y;
        const float dz = pz - q.z;
        const float d2 = dx * dx + dy * dy + dz * dz;
        cnt += (d2 <= r2) ? 1 : 0;
    }

    if (i < N && cnt != 0) atomicAdd(&out[i], cnt);
}

extern "C" void kernel_launch(void* const* d_in, const int* in_sizes, int n_in,
                              void* d_out, int out_size, void* d_ws, size_t ws_size,
                              hipStream_t stream) {
    const float* pc  = (const float*)d_in[0];   // [N,3]
    const float* pad = (const float*)d_in[1];   // [M,3]
    int* out = (int*)d_out;                      // [N] int32

    const int N = in_sizes[0] / 3;               // 20000
    const int M = in_sizes[1] / 3;               // 25000

    // d_out is poisoned 0xAA before every timed launch — zero it first.
    dens_zero_kernel<<<(N + BLOCK - 1) / BLOCK, BLOCK, 0, stream>>>(out, N);

    dim3 grid((N + BLOCK - 1) / BLOCK, (M + CHUNK - 1) / CHUNK);
    dens_count_kernel<<<grid, BLOCK, 0, stream>>>(pc, pad, out, N, M);
}

// Round 2
// 114.185 us; speedup vs baseline: 1.5333x; 1.5333x over previous
//
#include <hip/hip_runtime.h>

#define BLOCK 256
#define IPT   4              // i-points per thread
#define CHUNK 512            // padding points staged per block (8 KB LDS)

typedef float v2f __attribute__((ext_vector_type(2)));

__global__ void dens_zero_kernel(int* __restrict__ out, int n) {
    int i = blockIdx.x * blockDim.x + threadIdx.x;
    if (i < n) out[i] = 0;
}

__global__ __launch_bounds__(BLOCK) void dens_count_kernel(
    const float* __restrict__ pc,   // [N,3] pointcloud
    const float* __restrict__ pad,  // [M,3] pointcloud_padding
    int* __restrict__ out,          // [N] int32 counts
    int N, int M)
{
    __shared__ float4 s_pts[CHUNK];

    const int jstart = blockIdx.y * CHUNK;
    const int L      = min(CHUNK, M - jstart);

    // Stage chunk as (qx, qy, qz, negc) where negc = -( |q|^2 - r^2 ) / 2.
    // Condition  |p-q|^2 <= r^2  <=>  p.q + negc >= |p|^2/2
    for (int t = threadIdx.x; t < L; t += BLOCK) {
        const int j = jstart + t;
        const float qx = pad[3 * j], qy = pad[3 * j + 1], qz = pad[3 * j + 2];
        const float negc = 0.125f - 0.5f * (qx * qx + qy * qy + qz * qz);  // r^2/2 = 0.125
        s_pts[t] = make_float4(qx, qy, qz, negc);
    }
    __syncthreads();

    // Each thread owns IPT=4 points: i = ibase + k*BLOCK (coalesced per k).
    const int ibase = blockIdx.x * (BLOCK * IPT) + threadIdx.x;
    float px[IPT], py[IPT], pz[IPT], ha[IPT];
    #pragma unroll
    for (int k = 0; k < IPT; ++k) {
        const int i = ibase + k * BLOCK;
        if (i < N) {
            px[k] = pc[3 * i]; py[k] = pc[3 * i + 1]; pz[k] = pc[3 * i + 2];
            ha[k] = 0.5f * (px[k] * px[k] + py[k] * py[k] + pz[k] * pz[k]);
        } else {
            px[k] = py[k] = pz[k] = 0.0f;
            ha[k] = 3.0e38f;   // never satisfied -> cnt stays 0
        }
    }

    // Pack point-pairs for v_pk_fma_f32 dual-issue.
    const v2f pxA = {px[0], px[1]}, pyA = {py[0], py[1]}, pzA = {pz[0], pz[1]};
    const v2f pxB = {px[2], px[3]}, pyB = {py[2], py[3]}, pzB = {pz[2], pz[3]};

    int c0 = 0, c1 = 0, c2 = 0, c3 = 0;
    #pragma unroll 8
    for (int t = 0; t < L; ++t) {
        const float4 q = s_pts[t];   // uniform broadcast ds_read_b128
        v2f accA = pzA * q.z + q.w;  // fma chain; q.w = negc (scalar splat)
        accA     = pyA * q.y + accA;
        accA     = pxA * q.x + accA;
        v2f accB = pzB * q.z + q.w;
        accB     = pyB * q.y + accB;
        accB     = pxB * q.x + accB;
        c0 += (accA.x >= ha[0]);
        c1 += (accA.y >= ha[1]);
        c2 += (accB.x >= ha[2]);
        c3 += (accB.y >= ha[3]);
    }

    const int cnt[IPT] = {c0, c1, c2, c3};
    #pragma unroll
    for (int k = 0; k < IPT; ++k) {
        const int i = ibase + k * BLOCK;
        if (i < N && cnt[k] != 0) atomicAdd(&out[i], cnt[k]);
    }
}

extern "C" void kernel_launch(void* const* d_in, const int* in_sizes, int n_in,
                              void* d_out, int out_size, void* d_ws, size_t ws_size,
                              hipStream_t stream) {
    const float* pc  = (const float*)d_in[0];   // [N,3]
    const float* pad = (const float*)d_in[1];   // [M,3]
    int* out = (int*)d_out;                      // [N] int32

    const int N = in_sizes[0] / 3;               // 20000
    const int M = in_sizes[1] / 3;               // 25000

    // d_out is poisoned 0xAA before every timed launch — zero it first.
    dens_zero_kernel<<<(N + BLOCK - 1) / BLOCK, BLOCK, 0, stream>>>(out, N);

    dim3 grid((N + BLOCK * IPT - 1) / (BLOCK * IPT),  // 20
              (M + CHUNK - 1) / CHUNK);                // 49
    dens_count_kernel<<<grid, BLOCK, 0, stream>>>(pc, pad, out, N, M);
}